// Round 4
// baseline (378.445 us; speedup 1.0000x reference)
//
#include <hip/hip_runtime.h>
#include <stddef.h>

#define BB 32
#define NN 1024
#define HH 128

using f32x4 = __attribute__((ext_vector_type(4))) float;
using f16x8 = __attribute__((ext_vector_type(8))) _Float16;
using f16x4 = __attribute__((ext_vector_type(4))) _Float16;

// W^T in fp16, [p][n][k] = W_p[k][n]; p: 0=q, 1=k, 2=v.
__device__ _Float16 g_WT[3 * 128 * 128];

// ---------------- W transpose + cast to fp16 (tiny: 3 blocks) ----------------
__global__ __launch_bounds__(256) void wtrans_kernel(const float* __restrict__ Wq,
                                                     const float* __restrict__ Wk,
                                                     const float* __restrict__ Wv) {
    __shared__ float wl[128 * 128];
    const float* W = (blockIdx.x == 0) ? Wq : (blockIdx.x == 1) ? Wk : Wv;
    _Float16* dst = g_WT + blockIdx.x * 16384;
    const int tid = threadIdx.x;
    for (int i = tid; i < 4096; i += 256) ((f32x4*)wl)[i] = ((const f32x4*)W)[i];
    __syncthreads();
    for (int s = 0; s < 8; ++s) {
        int ch = tid + s * 256;
        int n = ch >> 4, kc = ch & 15;
        f16x8 v;
        #pragma unroll
        for (int j = 0; j < 8; ++j) v[j] = (_Float16)wl[(kc * 8 + j) * 128 + n];
        *(f16x8*)&dst[n * 128 + kc * 8] = v;
    }
}

// ---------------- Projection via MFMA ----------------
__global__ __launch_bounds__(256) void proj_kernel(
    const float* __restrict__ x,
    const float* __restrict__ bq, const float* __restrict__ bk, const float* __restrict__ bv,
    _Float16* __restrict__ qo, _Float16* __restrict__ ko, _Float16* __restrict__ vTo)
{
    __shared__ __align__(16) _Float16 rep[4][16 * 136];
    __shared__ __align__(16) _Float16 vsm[128 * 72];
    const int tid = threadIdx.x;
    const int w = tid >> 6, ln = tid & 63, qd = ln >> 4, l16 = ln & 15;
    const int row0 = blockIdx.x * 64;
    const int rw = row0 + w * 16;
    const int b = row0 >> 10, n0 = row0 & 1023;

    f16x8 xa[4];
    {
        const float* xr = x + (size_t)(rw + l16) * 128;
        #pragma unroll
        for (int t = 0; t < 4; ++t) {
            f32x4 a0 = *(const f32x4*)(xr + t * 32 + qd * 8);
            f32x4 a1 = *(const f32x4*)(xr + t * 32 + qd * 8 + 4);
            #pragma unroll
            for (int j = 0; j < 4; ++j) { xa[t][j] = (_Float16)a0[j]; xa[t][4 + j] = (_Float16)a1[j]; }
        }
    }

    for (int p = 0; p < 3; ++p) {
        const _Float16* Wt = g_WT + p * 16384;
        const float* bias = (p == 0) ? bq : (p == 1) ? bk : bv;

        float bv_[8];
        #pragma unroll
        for (int hc = 0; hc < 8; ++hc) bv_[hc] = bias[hc * 16 + l16];

        f32x4 acc[8];
        #pragma unroll
        for (int hc = 0; hc < 8; ++hc) {
            acc[hc] = (f32x4)(0.0f);
            #pragma unroll
            for (int t = 0; t < 4; ++t) {
                f16x8 bf = *(const f16x8*)(Wt + (size_t)(hc * 16 + l16) * 128 + t * 32 + qd * 8);
                acc[hc] = __builtin_amdgcn_mfma_f32_16x16x32_f16(xa[t], bf, acc[hc], 0, 0, 0);
            }
        }

        if (p < 2) {
            _Float16* dst = (p == 0) ? qo : ko;
            #pragma unroll
            for (int hc = 0; hc < 8; ++hc)
                #pragma unroll
                for (int r = 0; r < 4; ++r)
                    rep[w][(qd * 4 + r) * 136 + hc * 16 + l16] =
                        (_Float16)fmaxf(acc[hc][r] + bv_[hc], 0.0f);
            #pragma unroll
            for (int s = 0; s < 4; ++s) {
                int ch = ln + s * 64;
                int rr = ch >> 4, kc = ch & 15;
                f16x8 v = *(const f16x8*)&rep[w][rr * 136 + kc * 8];
                *(f16x8*)&dst[(size_t)(rw + rr) * 128 + kc * 8] = v;
            }
        } else {
            #pragma unroll
            for (int hc = 0; hc < 8; ++hc)
                #pragma unroll
                for (int r = 0; r < 4; ++r)
                    vsm[(hc * 16 + l16) * 72 + w * 16 + qd * 4 + r] =
                        (_Float16)fmaxf(acc[hc][r] + bv_[hc], 0.0f);
            __syncthreads();
            #pragma unroll
            for (int s = 0; s < 4; ++s) {
                int ch = tid + s * 256;
                int h = ch >> 3, g = ch & 7;
                f16x8 v = *(const f16x8*)&vsm[h * 72 + g * 8];
                *(f16x8*)&vTo[(size_t)b * HH * NN + (size_t)h * NN + n0 + g * 8] = v;
            }
        }
    }
}

// ---------------- Fused attention: S^T orientation, barrier-free ----------------
// grid (32, 32): 32-row i-groups x batch. 256 thr = 4 waves; pair = w>>1 (16 i-rows),
// half = w&1 (512 j-cols, 16 tiles of 32). No __syncthreads in the K-loop.
// S^T = K·Q^T: C-layout col = i (lane), row = j (quad*4+reg) -> softmax max needs
// only 2 shuffles; row-sum l is per-lane (reduced once at the end); rescale is one
// scalar per lane. Loads in-order-safe: vf(jt) | S eats kc | kc(jt+1) | softmax
// eats mv | mv(jt+1) | PV waits vf at vmcnt(16) -- prefetch never drains.
__global__ __launch_bounds__(256, 4) void attn_kernel(
    const _Float16* __restrict__ q, const _Float16* __restrict__ k,
    const _Float16* __restrict__ vT, const float* __restrict__ mask,
    float* __restrict__ out)
{
    __shared__ __align__(16) unsigned char smem[17920];
    _Float16* ps = (_Float16*)smem;      // [4 waves][16 i][stride 40 f16] = 5120 B
    float* mg = (float*)smem;            // merge overlay after the loop

    const int tid = threadIdx.x;
    const int w = tid >> 6, ln = tid & 63, qd = ln >> 4, l16 = ln & 15;
    const int pair = w >> 1, half = w & 1;
    const int b = blockIdx.y;
    const int i0 = blockIdx.x * 32 + pair * 16;

    _Float16* psw = ps + w * 640;

    // Q B-fragments (B[k][n]: n = l16 = i, k = qd*8+j -> identical addresses to A-frags)
    f16x8 qf[4];
    {
        const _Float16* qrow = q + ((size_t)b * NN + i0 + l16) * 128;
        #pragma unroll
        for (int t = 0; t < 4; ++t)
            qf[t] = *(const f16x8*)(qrow + t * 32 + qd * 8);
    }

    const _Float16* kbase = k + (size_t)b * NN * 128 + (size_t)half * 512 * 128;
    const _Float16* vbase = vT + (size_t)b * HH * NN + half * 512;
    const float* mbase = mask + (size_t)b * NN * NN + (size_t)(i0 + l16) * NN + half * 512;

    f32x4 acc[8];
    #pragma unroll
    for (int hc = 0; hc < 8; ++hc) acc[hc] = (f32x4)(0.0f);
    float m_i = -1e30f, l_i = 0.0f;    // per-lane: i = l16; m_i kept quad-uniform

    // preload tile 0: K A-frags (A[m][k]: m = l16 = j) + mask (4 consecutive j per load)
    f16x8 kc[8];
    #pragma unroll
    for (int c = 0; c < 2; ++c)
        #pragma unroll
        for (int t = 0; t < 4; ++t)
            kc[c * 4 + t] = *(const f16x8*)(kbase + (size_t)(c * 16 + l16) * 128 + t * 32 + qd * 8);
    f32x4 mv[2];
    #pragma unroll
    for (int c = 0; c < 2; ++c) mv[c] = *(const f32x4*)(mbase + c * 16 + qd * 4);

    for (int jt = 0; jt < 16; ++jt) {
        const int j0 = jt * 32;
        const int jn = (jt < 15) ? j0 + 32 : 0;   // wraps harmlessly on last iter

        // (1) V^T A-fragments for CURRENT tile — issued first (in-order vmcnt)
        f16x8 vf[8];
        #pragma unroll
        for (int hc = 0; hc < 8; ++hc)
            vf[hc] = *(const f16x8*)(vbase + (size_t)(hc * 16 + l16) * NN + j0 + qd * 8);

        // (2) S^T = K·Q^T : col = i = l16, row = j = qd*4+r (+16c)
        f32x4 s0 = (f32x4)(0.0f), s1 = (f32x4)(0.0f);
        #pragma unroll
        for (int t = 0; t < 4; ++t) {
            s0 = __builtin_amdgcn_mfma_f32_16x16x32_f16(kc[t],     qf[t], s0, 0, 0, 0);
            s1 = __builtin_amdgcn_mfma_f32_16x16x32_f16(kc[4 + t], qf[t], s1, 0, 0, 0);
        }

        // (3) reload kc in place for NEXT tile (kc fully consumed by S above)
        #pragma unroll
        for (int c = 0; c < 2; ++c)
            #pragma unroll
            for (int t = 0; t < 4; ++t)
                kc[c * 4 + t] = *(const f16x8*)(kbase + (size_t)(jn + c * 16 + l16) * 128 + t * 32 + qd * 8);

        // (4) mask + softmax: in-lane max (7 v_max) + 2 shuffles; no sum tree
        float lg[8];
        #pragma unroll
        for (int r = 0; r < 4; ++r) {
            lg[r]     = (mv[0][r] != 0.0f) ? s0[r] : -1e30f;
            lg[4 + r] = (mv[1][r] != 0.0f) ? s1[r] : -1e30f;
        }
        float tmax = lg[0];
        #pragma unroll
        for (int z = 1; z < 8; ++z) tmax = fmaxf(tmax, lg[z]);
        tmax = fmaxf(tmax, __shfl_xor(tmax, 16));
        tmax = fmaxf(tmax, __shfl_xor(tmax, 32));
        float mnew = fmaxf(m_i, tmax);
        float sc = __expf(m_i - mnew);
        float p[8], rs = 0.0f;
        #pragma unroll
        for (int z = 0; z < 8; ++z) { p[z] = __expf(lg[z] - mnew); rs += p[z]; }
        l_i = l_i * sc + rs;
        m_i = mnew;

        // (5) reload mask in place for NEXT tile
        #pragma unroll
        for (int c = 0; c < 2; ++c) mv[c] = *(const f32x4*)(mbase + jn + c * 16 + qd * 4);

        // (6) P -> LDS (P[i][j], j contiguous, stride 40 f16): two b64 writes
        f16x4 pk0, pk1;
        #pragma unroll
        for (int r = 0; r < 4; ++r) { pk0[r] = (_Float16)p[r]; pk1[r] = (_Float16)p[4 + r]; }
        *(f16x4*)&psw[l16 * 40 + qd * 4]      = pk0;
        *(f16x4*)&psw[l16 * 40 + 16 + qd * 4] = pk1;

        // (7) rescale accumulators (sc uniform per lane)
        #pragma unroll
        for (int hc = 0; hc < 8; ++hc) acc[hc] *= sc;

        // (8) O^T += V^T · P^T : B-frag = P[i=l16][j=qd*8..], one b128 read
        f16x8 pb = *(const f16x8*)&psw[l16 * 40 + qd * 8];
        #pragma unroll
        for (int hc = 0; hc < 8; ++hc)
            acc[hc] = __builtin_amdgcn_mfma_f32_16x16x32_f16(vf[hc], pb, acc[hc], 0, 0, 0);
    }

    // reduce l across quads (j-partition) — 2 shuffles, once
    l_i += __shfl_xor(l_i, 16);
    l_i += __shfl_xor(l_i, 32);

    // ---- merge the two j-halves (overlay on ps; stride 136 floats) ----
    __syncthreads();
    float* mgp = mg + pair * 2176;          // [16 i][136]
    float* ml  = mg + 4352;                 // [pair][{m,l}][16]
    if (half == 1) {
        #pragma unroll
        for (int hc = 0; hc < 8; ++hc)
            *(f32x4*)&mgp[l16 * 136 + hc * 16 + qd * 4] = acc[hc];
        if (qd == 0) {
            ml[pair * 32 + l16]      = m_i;
            ml[pair * 32 + 16 + l16] = l_i;
        }
    }
    __syncthreads();
    if (half == 0) {
        float m1  = ml[pair * 32 + l16];
        float l1v = ml[pair * 32 + 16 + l16];
        float M = fmaxf(m_i, m1);
        float a0 = __expf(m_i - M), a1 = __expf(m1 - M);
        float inv = 1.0f / (l_i * a0 + l1v * a1);
        a0 *= inv; a1 *= inv;
        float* orow = out + ((size_t)b * NN + i0 + l16) * 128;
        #pragma unroll
        for (int hc = 0; hc < 8; ++hc) {
            f32x4 o1 = *(const f32x4*)&mgp[l16 * 136 + hc * 16 + qd * 4];
            f32x4 o = acc[hc] * a0 + o1 * a1;
            *(f32x4*)&orow[hc * 16 + qd * 4] = o;
        }
    }
}

extern "C" void kernel_launch(void* const* d_in, const int* in_sizes, int n_in,
                              void* d_out, int out_size, void* d_ws, size_t ws_size,
                              hipStream_t stream) {
    const float* x    = (const float*)d_in[0];
    const float* mask = (const float*)d_in[1];
    const float* Wv   = (const float*)d_in[2];
    const float* bv   = (const float*)d_in[3];
    const float* Wk   = (const float*)d_in[4];
    const float* bk   = (const float*)d_in[5];
    const float* Wq   = (const float*)d_in[6];
    const float* bq   = (const float*)d_in[7];
    float* out = (float*)d_out;

    const size_t BNH = (size_t)BB * NN * HH;
    _Float16* ws  = (_Float16*)d_ws;
    _Float16* vTb = ws;                 // [B][H][N]
    _Float16* kb  = ws + BNH;           // [B][N][H]
    _Float16* qb  = ws + 2 * BNH;       // [B][N][H]

    wtrans_kernel<<<3, 256, 0, stream>>>(Wq, Wk, Wv);
    proj_kernel<<<512, 256, 0, stream>>>(x, bq, bk, bv, qb, kb, vTb);
    attn_kernel<<<dim3(32, 32), 256, 0, stream>>>(qb, kb, vTb, mask, out);
}

// Round 5
// 361.479 us; speedup vs baseline: 1.0469x; 1.0469x over previous
//
#include <hip/hip_runtime.h>
#include <stddef.h>

#define BB 32
#define NN 1024
#define HH 128

using f32x4 = __attribute__((ext_vector_type(4))) float;
using f16x8 = __attribute__((ext_vector_type(8))) _Float16;
using f16x4 = __attribute__((ext_vector_type(4))) _Float16;

// W^T in fp16, [p][n][k] = W_p[k][n]; p: 0=q, 1=k, 2=v.
__device__ _Float16 g_WT[3 * 128 * 128];

// ---------------- W transpose + cast to fp16 (tiny: 3 blocks) ----------------
__global__ __launch_bounds__(256) void wtrans_kernel(const float* __restrict__ Wq,
                                                     const float* __restrict__ Wk,
                                                     const float* __restrict__ Wv) {
    __shared__ float wl[128 * 128];
    const float* W = (blockIdx.x == 0) ? Wq : (blockIdx.x == 1) ? Wk : Wv;
    _Float16* dst = g_WT + blockIdx.x * 16384;
    const int tid = threadIdx.x;
    for (int i = tid; i < 4096; i += 256) ((f32x4*)wl)[i] = ((const f32x4*)W)[i];
    __syncthreads();
    for (int s = 0; s < 8; ++s) {
        int ch = tid + s * 256;
        int n = ch >> 4, kc = ch & 15;
        f16x8 v;
        #pragma unroll
        for (int j = 0; j < 8; ++j) v[j] = (_Float16)wl[(kc * 8 + j) * 128 + n];
        *(f16x8*)&dst[n * 128 + kc * 8] = v;
    }
}

// ---------------- Projection via MFMA ----------------
__global__ __launch_bounds__(256) void proj_kernel(
    const float* __restrict__ x,
    const float* __restrict__ bq, const float* __restrict__ bk, const float* __restrict__ bv,
    _Float16* __restrict__ qo, _Float16* __restrict__ ko, _Float16* __restrict__ vTo)
{
    __shared__ __align__(16) _Float16 rep[4][16 * 136];
    __shared__ __align__(16) _Float16 vsm[128 * 72];
    const int tid = threadIdx.x;
    const int w = tid >> 6, ln = tid & 63, qd = ln >> 4, l16 = ln & 15;
    const int row0 = blockIdx.x * 64;
    const int rw = row0 + w * 16;
    const int b = row0 >> 10, n0 = row0 & 1023;

    f16x8 xa[4];
    {
        const float* xr = x + (size_t)(rw + l16) * 128;
        #pragma unroll
        for (int t = 0; t < 4; ++t) {
            f32x4 a0 = *(const f32x4*)(xr + t * 32 + qd * 8);
            f32x4 a1 = *(const f32x4*)(xr + t * 32 + qd * 8 + 4);
            #pragma unroll
            for (int j = 0; j < 4; ++j) { xa[t][j] = (_Float16)a0[j]; xa[t][4 + j] = (_Float16)a1[j]; }
        }
    }

    for (int p = 0; p < 3; ++p) {
        const _Float16* Wt = g_WT + p * 16384;
        const float* bias = (p == 0) ? bq : (p == 1) ? bk : bv;

        float bv_[8];
        #pragma unroll
        for (int hc = 0; hc < 8; ++hc) bv_[hc] = bias[hc * 16 + l16];

        f32x4 acc[8];
        #pragma unroll
        for (int hc = 0; hc < 8; ++hc) {
            acc[hc] = (f32x4)(0.0f);
            #pragma unroll
            for (int t = 0; t < 4; ++t) {
                f16x8 bf = *(const f16x8*)(Wt + (size_t)(hc * 16 + l16) * 128 + t * 32 + qd * 8);
                acc[hc] = __builtin_amdgcn_mfma_f32_16x16x32_f16(xa[t], bf, acc[hc], 0, 0, 0);
            }
        }

        if (p < 2) {
            _Float16* dst = (p == 0) ? qo : ko;
            #pragma unroll
            for (int hc = 0; hc < 8; ++hc)
                #pragma unroll
                for (int r = 0; r < 4; ++r)
                    rep[w][(qd * 4 + r) * 136 + hc * 16 + l16] =
                        (_Float16)fmaxf(acc[hc][r] + bv_[hc], 0.0f);
            #pragma unroll
            for (int s = 0; s < 4; ++s) {
                int ch = ln + s * 64;
                int rr = ch >> 4, kc = ch & 15;
                f16x8 v = *(const f16x8*)&rep[w][rr * 136 + kc * 8];
                *(f16x8*)&dst[(size_t)(rw + rr) * 128 + kc * 8] = v;
            }
        } else {
            #pragma unroll
            for (int hc = 0; hc < 8; ++hc)
                #pragma unroll
                for (int r = 0; r < 4; ++r)
                    vsm[(hc * 16 + l16) * 72 + w * 16 + qd * 4 + r] =
                        (_Float16)fmaxf(acc[hc][r] + bv_[hc], 0.0f);
            __syncthreads();
            #pragma unroll
            for (int s = 0; s < 4; ++s) {
                int ch = tid + s * 256;
                int h = ch >> 3, g = ch & 7;
                f16x8 v = *(const f16x8*)&vsm[h * 72 + g * 8];
                *(f16x8*)&vTo[(size_t)b * HH * NN + (size_t)h * NN + n0 + g * 8] = v;
            }
        }
    }
}

// ---------------- Fused attention: S^T orientation, barrier-free ----------------
// grid (32, 32). 256 thr = 4 waves; pair = w>>1 (16 i-rows), half = w&1 (512 j).
// No __syncthreads in the K-loop; only LDS use is the wave-private P round-trip.
// Issue order per iter: vf(jt) -> kc(jt+1) -> mask(jt+2); consumption order
// kc(jt) [oldest], mask(jt) [retired long ago], vf(jt) [retires only mask(jt+1)]
// -- so the in-order vmcnt never drains the prefetch queue.
// __launch_bounds__(256,2): 256-reg cap. (256,4) in R4 forced 128 -> scratch
// spills (FETCH +22MB, WRITE +18MB, VALUBusy 9%). ~150 regs -> 3 waves/SIMD.
__global__ __launch_bounds__(256, 2) void attn_kernel(
    const _Float16* __restrict__ q, const _Float16* __restrict__ k,
    const _Float16* __restrict__ vT, const float* __restrict__ mask,
    float* __restrict__ out)
{
    __shared__ __align__(16) unsigned char smem[17920];
    _Float16* ps = (_Float16*)smem;      // [4 waves][16 i][stride 40 f16] = 5120 B
    float* mg = (float*)smem;            // merge overlay after the loop

    const int tid = threadIdx.x;
    const int w = tid >> 6, ln = tid & 63, qd = ln >> 4, l16 = ln & 15;
    const int pair = w >> 1, half = w & 1;
    const int b = blockIdx.y;
    const int i0 = blockIdx.x * 32 + pair * 16;

    _Float16* psw = ps + w * 640;

    // Q B-fragments (n = l16 = i, k = qd*8+j)
    f16x8 qf[4];
    {
        const _Float16* qrow = q + ((size_t)b * NN + i0 + l16) * 128;
        #pragma unroll
        for (int t = 0; t < 4; ++t)
            qf[t] = *(const f16x8*)(qrow + t * 32 + qd * 8);
    }

    const _Float16* kbase = k + (size_t)b * NN * 128 + (size_t)half * 512 * 128;
    const _Float16* vbase = vT + (size_t)b * HH * NN + half * 512;
    const float* mbase = mask + (size_t)b * NN * NN + (size_t)(i0 + l16) * NN + half * 512;

    f32x4 acc[8];
    #pragma unroll
    for (int hc = 0; hc < 8; ++hc) acc[hc] = (f32x4)(0.0f);
    float m_i = -1e30f, l_i = 0.0f;    // per-lane (i = l16); m_i quad-uniform

    // preload: K A-frags tile0, mask tiles 0 and 1 (ring, distance 2)
    f16x8 kc[8];
    #pragma unroll
    for (int c = 0; c < 2; ++c)
        #pragma unroll
        for (int t = 0; t < 4; ++t)
            kc[c * 4 + t] = *(const f16x8*)(kbase + (size_t)(c * 16 + l16) * 128 + t * 32 + qd * 8);
    f32x4 mring[2][2];
    #pragma unroll
    for (int c = 0; c < 2; ++c) {
        mring[0][c] = *(const f32x4*)(mbase + c * 16 + qd * 4);
        mring[1][c] = *(const f32x4*)(mbase + 32 + c * 16 + qd * 4);
    }

    #pragma unroll
    for (int jt = 0; jt < 16; ++jt) {
        const int j0 = jt * 32;
        const int jn = (jt < 15) ? j0 + 32 : 0;    // kc reload target (wraps)
        const int jm = (jt < 14) ? j0 + 64 : 0;    // mask reload target (wraps)
        const int cur = jt & 1;

        // (1) V^T A-fragments for CURRENT tile — issued first
        f16x8 vf[8];
        #pragma unroll
        for (int hc = 0; hc < 8; ++hc)
            vf[hc] = *(const f16x8*)(vbase + (size_t)(hc * 16 + l16) * NN + j0 + qd * 8);

        // (2) S^T = K·Q^T : col = i = l16, row = j = qd*4+r (+16c)
        f32x4 s0 = (f32x4)(0.0f), s1 = (f32x4)(0.0f);
        #pragma unroll
        for (int t = 0; t < 4; ++t) {
            s0 = __builtin_amdgcn_mfma_f32_16x16x32_f16(kc[t],     qf[t], s0, 0, 0, 0);
            s1 = __builtin_amdgcn_mfma_f32_16x16x32_f16(kc[4 + t], qf[t], s1, 0, 0, 0);
        }

        // (3) reload kc in place for NEXT tile (consumed by S above)
        #pragma unroll
        for (int c = 0; c < 2; ++c)
            #pragma unroll
            for (int t = 0; t < 4; ++t)
                kc[c * 4 + t] = *(const f16x8*)(kbase + (size_t)(jn + c * 16 + l16) * 128 + t * 32 + qd * 8);

        // (4) mask + softmax: 7 in-lane v_max + 2 shuffles; no sum tree
        float lg[8];
        #pragma unroll
        for (int r = 0; r < 4; ++r) {
            lg[r]     = (mring[cur][0][r] != 0.0f) ? s0[r] : -1e30f;
            lg[4 + r] = (mring[cur][1][r] != 0.0f) ? s1[r] : -1e30f;
        }
        // (5) reload mask tile jt+2 into the slot just consumed
        #pragma unroll
        for (int c = 0; c < 2; ++c)
            mring[cur][c] = *(const f32x4*)(mbase + jm + c * 16 + qd * 4);

        float tmax = lg[0];
        #pragma unroll
        for (int z = 1; z < 8; ++z) tmax = fmaxf(tmax, lg[z]);
        tmax = fmaxf(tmax, __shfl_xor(tmax, 16));
        tmax = fmaxf(tmax, __shfl_xor(tmax, 32));
        float mnew = fmaxf(m_i, tmax);
        float sc = __expf(m_i - mnew);
        float p[8], rs = 0.0f;
        #pragma unroll
        for (int z = 0; z < 8; ++z) { p[z] = __expf(lg[z] - mnew); rs += p[z]; }
        l_i = l_i * sc + rs;
        m_i = mnew;

        // (6) P -> LDS (P[i=l16][j], stride 40 f16): two b64 writes
        f16x4 pk0, pk1;
        #pragma unroll
        for (int r = 0; r < 4; ++r) { pk0[r] = (_Float16)p[r]; pk1[r] = (_Float16)p[4 + r]; }
        *(f16x4*)&psw[l16 * 40 + qd * 4]      = pk0;
        *(f16x4*)&psw[l16 * 40 + 16 + qd * 4] = pk1;

        // (7) rescale accumulators (sc uniform per lane)
        #pragma unroll
        for (int hc = 0; hc < 8; ++hc) acc[hc] *= sc;

        // (8) O^T += V^T · P^T : B-frag = P[i=l16][j=qd*8..], one b128 read
        f16x8 pb = *(const f16x8*)&psw[l16 * 40 + qd * 8];
        #pragma unroll
        for (int hc = 0; hc < 8; ++hc)
            acc[hc] = __builtin_amdgcn_mfma_f32_16x16x32_f16(vf[hc], pb, acc[hc], 0, 0, 0);
    }

    // reduce l across quads (j-partition) — 2 shuffles, once
    l_i += __shfl_xor(l_i, 16);
    l_i += __shfl_xor(l_i, 32);

    // ---- merge the two j-halves (overlay on ps; stride 136 floats) ----
    __syncthreads();
    float* mgp = mg + pair * 2176;          // [16 i][136]
    float* ml  = mg + 4352;                 // [pair][{m,l}][16]
    if (half == 1) {
        #pragma unroll
        for (int hc = 0; hc < 8; ++hc)
            *(f32x4*)&mgp[l16 * 136 + hc * 16 + qd * 4] = acc[hc];
        if (qd == 0) {
            ml[pair * 32 + l16]      = m_i;
            ml[pair * 32 + 16 + l16] = l_i;
        }
    }
    __syncthreads();
    if (half == 0) {
        float m1  = ml[pair * 32 + l16];
        float l1v = ml[pair * 32 + 16 + l16];
        float M = fmaxf(m_i, m1);
        float a0 = __expf(m_i - M), a1 = __expf(m1 - M);
        float inv = 1.0f / (l_i * a0 + l1v * a1);
        a0 *= inv; a1 *= inv;
        float* orow = out + ((size_t)b * NN + i0 + l16) * 128;
        #pragma unroll
        for (int hc = 0; hc < 8; ++hc) {
            f32x4 o1 = *(const f32x4*)&mgp[l16 * 136 + hc * 16 + qd * 4];
            f32x4 o = acc[hc] * a0 + o1 * a1;
            *(f32x4*)&orow[hc * 16 + qd * 4] = o;
        }
    }
}

extern "C" void kernel_launch(void* const* d_in, const int* in_sizes, int n_in,
                              void* d_out, int out_size, void* d_ws, size_t ws_size,
                              hipStream_t stream) {
    const float* x    = (const float*)d_in[0];
    const float* mask = (const float*)d_in[1];
    const float* Wv   = (const float*)d_in[2];
    const float* bv   = (const float*)d_in[3];
    const float* Wk   = (const float*)d_in[4];
    const float* bk   = (const float*)d_in[5];
    const float* Wq   = (const float*)d_in[6];
    const float* bq   = (const float*)d_in[7];
    float* out = (float*)d_out;

    const size_t BNH = (size_t)BB * NN * HH;
    _Float16* ws  = (_Float16*)d_ws;
    _Float16* vTb = ws;                 // [B][H][N]
    _Float16* kb  = ws + BNH;           // [B][N][H]
    _Float16* qb  = ws + 2 * BNH;       // [B][N][H]

    wtrans_kernel<<<3, 256, 0, stream>>>(Wq, Wk, Wv);
    proj_kernel<<<512, 256, 0, stream>>>(x, bq, bk, bv, qb, kb, vTb);
    attn_kernel<<<dim3(32, 32), 256, 0, stream>>>(qb, kb, vTb, mask, out);
}